// Round 6
// baseline (1718.661 us; speedup 1.0000x reference)
//
#include <hip/hip_runtime.h>
#include <hip/hip_bf16.h>
#include <math.h>

// Problem constants
#define T_STEPS 64
#define NN      2048
#define KN      32
#define IND     256
#define H1D     128
#define C1D     384   // HEADS*H1
#define H2D     128
#define GD      256
#define PD      60
#define GRU_NB  8     // cooperating blocks for the GRU

// bit-reversed 5-bit order (involution): loading rows in this order makes
// lane l end up owning neighbor l's dot after the butterfly reduce.
#define BITREV5_INIT {0,16,8,24,4,20,12,28,2,18,10,26,6,22,14,30, \
                      1,17,9,25,5,21,13,29,3,19,11,27,7,23,15,31}

// Butterfly stages 2..6 on 16 stage-1-combined partials.
// Input: part[i] = stage-1 combine of slots (BR[i], BR[i+16]).
// Output: lane l holds full 64-lane sum of slot (l & 31).
__device__ __forceinline__ float xpose_reduce16(float part[16], int lane) {
#pragma unroll
    for (int i = 0; i < 8; ++i) {
        float send = (lane & 2) ? part[i] : part[i + 8];
        float keep = (lane & 2) ? part[i + 8] : part[i];
        part[i] = keep + __shfl_xor(send, 2);
    }
#pragma unroll
    for (int i = 0; i < 4; ++i) {
        float send = (lane & 4) ? part[i] : part[i + 4];
        float keep = (lane & 4) ? part[i + 4] : part[i];
        part[i] = keep + __shfl_xor(send, 4);
    }
#pragma unroll
    for (int i = 0; i < 2; ++i) {
        float send = (lane & 8) ? part[i] : part[i + 2];
        float keep = (lane & 8) ? part[i + 2] : part[i];
        part[i] = keep + __shfl_xor(send, 8);
    }
    {
        float send = (lane & 16) ? part[0] : part[1];
        float keep = (lane & 16) ? part[1] : part[0];
        part[0] = keep + __shfl_xor(send, 16);
    }
    return part[0] + __shfl_xor(part[0], 32);
}

// ---------------------------------------------------------------------------
// K1: row norms of h[t]  (one wave per node)
// ---------------------------------------------------------------------------
__global__ __launch_bounds__(256) void norms_kernel(const float* __restrict__ h,
                                                    float* __restrict__ norms,
                                                    int t_base) {
    int gw   = (int)((blockIdx.x * blockDim.x + threadIdx.x) >> 6);
    int lane = threadIdx.x & 63;
    int n    = gw & (NN - 1);
    int tloc = gw >> 11;
    const float* row = h + ((size_t)(t_base + tloc) * NN + n) * IND;
    float s = 0.f;
#pragma unroll
    for (int q = 0; q < 4; ++q) { float v = row[lane + 64 * q]; s += v * v; }
#pragma unroll
    for (int off = 32; off > 0; off >>= 1) s += __shfl_xor(s, off);
    if (lane == 0) norms[(size_t)tloc * NN + n] = sqrtf(s);
}

// ---------------------------------------------------------------------------
// K2: input attention. 2 waves per (t,n) (128 dims each); rows kept in VGPRs,
// half-dots combined through LDS. No re-read in phase B.
// ---------------------------------------------------------------------------
__global__ __launch_bounds__(256) void input_attn_kernel(const float* __restrict__ h,
                                                         const int* __restrict__ neigh,
                                                         const float* __restrict__ norms,
                                                         float* __restrict__ ih,
                                                         int t_base) {
    const int BR[32] = BITREV5_INIT;
    __shared__ float hd_s[2][2][32];
    int wave    = threadIdx.x >> 6;   // 0..3
    int nodeloc = wave >> 1;          // 0..1
    int half    = wave & 1;           // which 128-dim half
    int lane    = threadIdx.x & 63;
    int gw   = (int)((blockIdx.x << 1) | nodeloc);
    int n    = gw & (NN - 1);
    int tloc = gw >> 11;
    const float* hT  = h + (size_t)(t_base + tloc) * NN * IND;
    const float* nrm = norms + (size_t)tloc * NN;

    const float* dst = hT + (size_t)n * IND + half * 128;
    float d0 = dst[lane], d1 = dst[lane + 64];

    int   jreg = neigh[n * KN + (lane & 31)];
    float nj   = nrm[jreg];
    float ndst = nrm[n];

    float r0[32], r1[32], comb[16];
#pragma unroll
    for (int i = 0; i < 16; ++i) {
        int ja = __shfl(jreg, BR[i]);
        int jb = __shfl(jreg, BR[i + 16]);
        const float* sa = hT + (size_t)ja * IND + half * 128;
        const float* sb = hT + (size_t)jb * IND + half * 128;
        r0[i]      = sa[lane]; r1[i]      = sa[lane + 64];
        r0[i + 16] = sb[lane]; r1[i + 16] = sb[lane + 64];
        float pa = r0[i] * d0 + r1[i] * d1;
        float pb = r0[i + 16] * d0 + r1[i + 16] * d1;
        float send = (lane & 1) ? pa : pb;
        float keep = (lane & 1) ? pb : pa;
        comb[i] = keep + __shfl_xor(send, 1);
    }
    float hdot = xpose_reduce16(comb, lane);   // half-dot of neighbor (lane&31)
    if (lane < 32) hd_s[nodeloc][half][lane] = hdot;
    __syncthreads();
    float dot = hdot + hd_s[nodeloc][half ^ 1][lane & 31];

    float r  = dot / (nj * ndst);
    float r2 = r * r;
    float e  = r2 * r2;

    float a0 = 0.f, a1 = 0.f;
#pragma unroll
    for (int i = 0; i < 32; ++i) {
        float ek = __shfl(e, BR[i]);
        a0 += ek * r0[i];
        a1 += ek * r1[i];
    }
    float* orow = ih + (size_t)gw * IND + half * 128;
    orow[lane]      = a0;
    orow[lane + 64] = a1;
}

// ---------------------------------------------------------------------------
// K3/K6: generic fp32 tiled GEMM  C[M,N] = A[M,K] @ B[K,N]
// ---------------------------------------------------------------------------
__global__ __launch_bounds__(256) void matmul_f32(const float* __restrict__ A,
                                                  const float* __restrict__ B,
                                                  float* __restrict__ C,
                                                  int M, int N, int K) {
    __shared__ float As[16][65];
    __shared__ float Bs[16][68];
    int tid  = threadIdx.x;
    int row0 = blockIdx.y * 64;
    int col0 = blockIdx.x * 64;
    int tr = tid >> 4, tc = tid & 15;
    float acc[4][4] = {};
    int la_m = tid >> 2;
    int la_k = (tid & 3) * 4;
    int lb_k = tid >> 4;
    int lb_n = (tid & 15) * 4;
    for (int k0 = 0; k0 < K; k0 += 16) {
        float4 av = *(const float4*)(A + (size_t)(row0 + la_m) * K + k0 + la_k);
        float4 bv = *(const float4*)(B + (size_t)(k0 + lb_k) * N + col0 + lb_n);
        __syncthreads();
        As[la_k + 0][la_m] = av.x; As[la_k + 1][la_m] = av.y;
        As[la_k + 2][la_m] = av.z; As[la_k + 3][la_m] = av.w;
        *(float4*)&Bs[lb_k][lb_n] = bv;
        __syncthreads();
#pragma unroll
        for (int kk = 0; kk < 16; ++kk) {
            float a[4], b[4];
#pragma unroll
            for (int r = 0; r < 4; ++r) a[r] = As[kk][tr * 4 + r];
#pragma unroll
            for (int c = 0; c < 4; ++c) b[c] = Bs[kk][tc * 4 + c];
#pragma unroll
            for (int r = 0; r < 4; ++r)
#pragma unroll
                for (int c = 0; c < 4; ++c) acc[r][c] += a[r] * b[c];
        }
    }
#pragma unroll
    for (int r = 0; r < 4; ++r) {
        float4 v = { acc[r][0], acc[r][1], acc[r][2], acc[r][3] };
        *(float4*)(C + (size_t)(row0 + tr * 4 + r) * N + col0 + tc * 4) = v;
    }
}

// ---------------------------------------------------------------------------
// K4: 3-head GAT + relu. One block (192 thr, wave=head) per (t,n), lane=d.
// Rows kept in VGPRs; phase B is register-only.
// ---------------------------------------------------------------------------
__global__ __launch_bounds__(192) void gat_heads_kernel(const float* __restrict__ z1,
                                                        const int* __restrict__ neigh,
                                                        float* __restrict__ c) {
    const int BR[32] = BITREV5_INIT;
    int n    = blockIdx.x & (NN - 1);
    const float* ztbl = z1 + (size_t)(blockIdx.x >> 11) * NN * C1D;
    int head = threadIdx.x >> 6;
    int lane = threadIdx.x & 63;

    const float* dst = ztbl + (size_t)n * C1D + head * H1D;
    float d0 = dst[lane], d1 = dst[lane + 64];
    int jreg = neigh[n * KN + (lane & 31)];

    float r0[32], r1[32], comb[16];
#pragma unroll
    for (int i = 0; i < 16; ++i) {
        int ja = __shfl(jreg, BR[i]);
        int jb = __shfl(jreg, BR[i + 16]);
        const float* sa = ztbl + (size_t)ja * C1D + head * H1D;
        const float* sb = ztbl + (size_t)jb * C1D + head * H1D;
        r0[i]      = sa[lane]; r1[i]      = sa[lane + 64];
        r0[i + 16] = sb[lane]; r1[i + 16] = sb[lane + 64];
        float pa = r0[i] * d0 + r1[i] * d1;
        float pb = r0[i + 16] * d0 + r1[i + 16] * d1;
        float send = (lane & 1) ? pa : pb;
        float keep = (lane & 1) ? pb : pa;
        comb[i] = keep + __shfl_xor(send, 1);
    }
    float dot = xpose_reduce16(comb, lane);   // lane l: dot of neighbor (l&31)

    float m = dot;
#pragma unroll
    for (int off = 16; off > 0; off >>= 1) m = fmaxf(m, __shfl_xor(m, off));
    float p = __expf(dot - m);
    float s = p;
#pragma unroll
    for (int off = 16; off > 0; off >>= 1) s += __shfl_xor(s, off);
    p /= s;

    float a0 = 0.f, a1 = 0.f;
#pragma unroll
    for (int i = 0; i < 32; ++i) {
        float pk = __shfl(p, BR[i]);
        a0 += pk * r0[i];
        a1 += pk * r1[i];
    }
    size_t base = (size_t)blockIdx.x * C1D + (size_t)head * H1D;
    c[base + lane]      = fmaxf(a0, 0.f);
    c[base + lane + 64] = fmaxf(a1, 0.f);
}

// ---------------------------------------------------------------------------
// K7: final GAT on z2 (d=128) + relu -> c2. One wave per (t,n), rows in VGPRs.
// ---------------------------------------------------------------------------
__global__ __launch_bounds__(256) void gat_final_kernel(const float* __restrict__ z2,
                                                        const int* __restrict__ neigh,
                                                        float* __restrict__ c2) {
    const int BR[32] = BITREV5_INIT;
    int gw   = (int)((blockIdx.x << 2) | (threadIdx.x >> 6));
    int n    = gw & (NN - 1);
    const float* ztbl = z2 + (size_t)(gw >> 11) * NN * H2D;
    int lane = threadIdx.x & 63;

    const float* dst = ztbl + (size_t)n * H2D;
    float d0 = dst[lane], d1 = dst[lane + 64];
    int jreg = neigh[n * KN + (lane & 31)];

    float r0[32], r1[32], comb[16];
#pragma unroll
    for (int i = 0; i < 16; ++i) {
        int ja = __shfl(jreg, BR[i]);
        int jb = __shfl(jreg, BR[i + 16]);
        const float* sa = ztbl + (size_t)ja * H2D;
        const float* sb = ztbl + (size_t)jb * H2D;
        r0[i]      = sa[lane]; r1[i]      = sa[lane + 64];
        r0[i + 16] = sb[lane]; r1[i + 16] = sb[lane + 64];
        float pa = r0[i] * d0 + r1[i] * d1;
        float pb = r0[i + 16] * d0 + r1[i + 16] * d1;
        float send = (lane & 1) ? pa : pb;
        float keep = (lane & 1) ? pb : pa;
        comb[i] = keep + __shfl_xor(send, 1);
    }
    float dot = xpose_reduce16(comb, lane);

    float m = dot;
#pragma unroll
    for (int off = 16; off > 0; off >>= 1) m = fmaxf(m, __shfl_xor(m, off));
    float p = __expf(dot - m);
    float s = p;
#pragma unroll
    for (int off = 16; off > 0; off >>= 1) s += __shfl_xor(s, off);
    p /= s;

    float a0 = 0.f, a1 = 0.f;
#pragma unroll
    for (int i = 0; i < 32; ++i) {
        float pk = __shfl(p, BR[i]);
        a0 += pk * r0[i];
        a1 += pk * r1[i];
    }
    c2[(size_t)gw * H2D + lane]      = fmaxf(a0, 0.f);
    c2[(size_t)gw * H2D + lane + 64] = fmaxf(a1, 0.f);
}

// ---------------------------------------------------------------------------
// K8: pooled[t][j] = max_n c2[t][n][j]  — two stage for grid parallelism
// ---------------------------------------------------------------------------
__global__ __launch_bounds__(128) void pool_part_kernel(const float* __restrict__ c2,
                                                        float* __restrict__ ppart) {
    int j = threadIdx.x;
    int tloc  = blockIdx.x >> 4;
    int slice = blockIdx.x & 15;
    const float* base = c2 + ((size_t)tloc * NN + slice * 128) * H2D;
    float mx = 0.f;
    for (int q = 0; q < 128; ++q) mx = fmaxf(mx, base[(size_t)q * H2D + j]);
    ppart[(size_t)blockIdx.x * H2D + j] = mx;
}
__global__ __launch_bounds__(128) void pool_reduce_kernel(const float* __restrict__ ppart,
                                                          float* __restrict__ pooled,
                                                          int t_base) {
    int j = threadIdx.x;
    const float* base = ppart + (size_t)blockIdx.x * 16 * H2D;
    float mx = 0.f;
#pragma unroll
    for (int q = 0; q < 16; ++q) mx = fmaxf(mx, base[(size_t)q * H2D + j]);
    pooled[(t_base + blockIdx.x) * H2D + j] = mx;
}

// ---------------------------------------------------------------------------
// prep: fc1 (3,256,128) -> W1 (256,384); zero GRU arrival counters
// ---------------------------------------------------------------------------
__global__ void prep_W1(const float* __restrict__ fc1, float* __restrict__ W1,
                        unsigned int* __restrict__ cnt) {
    int i = blockIdx.x * 256 + threadIdx.x;
    if (i < 256 * 384) {
        int d = i / 384, cf = i % 384;
        int hd = cf >> 7, j = cf & 127;
        W1[i] = fc1[(size_t)hd * 256 * 128 + (size_t)d * 128 + j];
    }
    if (i < T_STEPS) cnt[i] = 0u;
}

// ---------------------------------------------------------------------------
// gi_all[t][o] = Wih[o,:] . pooled[t,:] + bih[o]   (parallel over t)
// ---------------------------------------------------------------------------
__global__ __launch_bounds__(256) void gi_all_kernel(const float* __restrict__ Wih,
                                                     const float* __restrict__ bih,
                                                     const float* __restrict__ pooled,
                                                     float* __restrict__ gi_all) {
    __shared__ float p_s[H2D];
    int t  = blockIdx.x / 3;
    int ob = (blockIdx.x % 3) * 256;
    if (threadIdx.x < H2D) p_s[threadIdx.x] = pooled[t * H2D + threadIdx.x];
    __syncthreads();
    int o = ob + threadIdx.x;
    float acc = bih[o];
    const float* wr = Wih + (size_t)o * H2D;
#pragma unroll 4
    for (int d = 0; d < H2D; ++d) acc += wr[d] * p_s[d];
    gi_all[t * 768 + o] = acc;
}

// ---------------------------------------------------------------------------
// GRU: 8 cooperating blocks, Whh register-resident (no per-step weight re-read).
// ---------------------------------------------------------------------------
__global__ __launch_bounds__(768) void gru_reg_kernel(const float* __restrict__ Whh,
                                                      const float* __restrict__ bhh,
                                                      const float* __restrict__ gi_all,
                                                      const float* __restrict__ hx0,
                                                      float* hx_all,
                                                      unsigned int* cnt) {
    __shared__ float4 hx_pad[72];                 // padded: idx (g,i) -> g*9+i
    __shared__ __align__(16) float hx_lin[GD];    // linear copy for hx_old
    __shared__ float gh_s[96];
    int b   = blockIdx.x;
    int tid = threadIdx.x;
    int row_local = tid >> 3;      // 0..95
    int sub       = tid & 7;       // 0..7
    int chunk     = row_local >> 5;
    int r_in      = row_local & 31;
    int grow      = chunk * GD + b * 32 + r_in;

    float4 wreg[8];
    const float4* wrow = (const float4*)(Whh + (size_t)grow * GD + sub * 32);
#pragma unroll
    for (int i = 0; i < 8; ++i) wreg[i] = wrow[i];
    float bias = (sub == 0) ? bhh[grow] : 0.f;

    for (int t = 0; t < T_STEPS; ++t) {
        if (t > 0) {
            if (tid == 0) {
                while (__hip_atomic_load(&cnt[t - 1], __ATOMIC_ACQUIRE,
                                         __HIP_MEMORY_SCOPE_AGENT) < GRU_NB)
                    __builtin_amdgcn_s_sleep(1);
            }
            __syncthreads();
        }
        const float* hsrc = (t == 0) ? hx0 : (hx_all + (size_t)(t - 1) * GD);
        if (tid < 64) {
            float4 v;
            v.x = __hip_atomic_load(hsrc + tid * 4 + 0, __ATOMIC_RELAXED, __HIP_MEMORY_SCOPE_AGENT);
            v.y = __hip_atomic_load(hsrc + tid * 4 + 1, __ATOMIC_RELAXED, __HIP_MEMORY_SCOPE_AGENT);
            v.z = __hip_atomic_load(hsrc + tid * 4 + 2, __ATOMIC_RELAXED, __HIP_MEMORY_SCOPE_AGENT);
            v.w = __hip_atomic_load(hsrc + tid * 4 + 3, __ATOMIC_RELAXED, __HIP_MEMORY_SCOPE_AGENT);
            hx_pad[(tid >> 3) * 9 + (tid & 7)] = v;
            ((float4*)hx_lin)[tid] = v;
        }
        __syncthreads();

        float acc = 0.f;
#pragma unroll
        for (int i = 0; i < 8; ++i) {
            float4 hv = hx_pad[sub * 9 + i];
            float4 wv = wreg[i];
            acc += wv.x * hv.x + wv.y * hv.y + wv.z * hv.z + wv.w * hv.w;
        }
        acc += __shfl_xor(acc, 1);
        acc += __shfl_xor(acc, 2);
        acc += __shfl_xor(acc, 4);
        if (sub == 0) gh_s[row_local] = acc + bias;
        __syncthreads();

        if (tid < 32) {
            int u = b * 32 + tid;
            float gi_r = gi_all[t * 768 + u];
            float gi_z = gi_all[t * 768 + 256 + u];
            float gi_n = gi_all[t * 768 + 512 + u];
            float r  = 1.f / (1.f + expf(-(gi_r + gh_s[tid])));
            float zg = 1.f / (1.f + expf(-(gi_z + gh_s[32 + tid])));
            float nn = tanhf(gi_n + r * gh_s[64 + tid]);
            float hnew = (1.f - zg) * nn + zg * hx_lin[u];
            __hip_atomic_store(&hx_all[(size_t)t * GD + u], hnew,
                               __ATOMIC_RELAXED, __HIP_MEMORY_SCOPE_AGENT);
            __threadfence();
        }
        __syncthreads();
        if (tid == 0)
            __hip_atomic_fetch_add(&cnt[t], 1u, __ATOMIC_RELEASE,
                                   __HIP_MEMORY_SCOPE_AGENT);
    }
}

// ---------------------------------------------------------------------------
// res heads + SIR scan. One block per t.
// ---------------------------------------------------------------------------
__global__ __launch_bounds__(128) void res_sir_kernel(const float* __restrict__ hx_all,
                                                      const float* __restrict__ It,
                                                      const float* __restrict__ Rt,
                                                      const float* __restrict__ r1W,
                                                      const float* __restrict__ r1b,
                                                      const float* __restrict__ r2W,
                                                      const float* __restrict__ r2b,
                                                      const float* __restrict__ I,
                                                      const float* __restrict__ R,
                                                      const float* __restrict__ S,
                                                      const float* __restrict__ Npop,
                                                      float* __restrict__ out) {
    __shared__ float nhx[258];
    __shared__ float ab_s[2];
    int t = blockIdx.x, tid = threadIdx.x;
    for (int i = tid; i < GD; i += 128) nhx[i] = hx_all[t * GD + i];
    if (tid == 0) { nhx[256] = It[t]; nhx[257] = Rt[t]; }
    __syncthreads();
    if (tid < 120) {
        float acc = r1b[tid];
        const float* wr = r1W + tid * 258;
        for (int d = 0; d < 258; ++d) acc += wr[d] * nhx[d];
        int idx = t * 60 + (tid >> 1);
        if (tid & 1) out[3840 + idx] = acc;
        else         out[idx] = acc;
    }
    if (tid == 120 || tid == 121) {
        int q = tid - 120;
        float acc = r2b[q];
        const float* wr = r2W + q * 258;
        for (int d = 0; d < 258; ++d) acc += wr[d] * nhx[d];
        ab_s[q] = acc;
    }
    __syncthreads();
    if (tid == 0) {
        float a_s = 1.f / (1.f + expf(-ab_s[0]));
        float b_s = 1.f / (1.f + expf(-ab_s[1]));
        float Np = Npop[0];
        float lI = I[t], lR = R[t], lS = S[t];
        for (int p = 0; p < PD; ++p) {
            float dI = a_s * lI * (lS / Np) - b_s * lI;
            float dR = b_s * lI;
            lI += dI;
            lR += dR;
            lS = Np - lI - lR;
            out[7680  + t * 60 + p] = dI;
            out[11520 + t * 60 + p] = dR;
        }
    }
}

// ---------------------------------------------------------------------------
extern "C" void kernel_launch(void* const* d_in, const int* in_sizes, int n_in,
                              void* d_out, int out_size, void* d_ws, size_t ws_size,
                              hipStream_t stream) {
    const float* h    = (const float*)d_in[0];
    const int*   ng   = (const int*)  d_in[1];
    const float* Npop = (const float*)d_in[2];
    const float* I_   = (const float*)d_in[3];
    const float* R_   = (const float*)d_in[4];
    const float* S_   = (const float*)d_in[5];
    const float* It   = (const float*)d_in[6];
    const float* Rt   = (const float*)d_in[7];
    const float* fc1  = (const float*)d_in[8];
    const float* fc2  = (const float*)d_in[9];
    const float* gWih = (const float*)d_in[10];
    const float* gWhh = (const float*)d_in[11];
    const float* gbih = (const float*)d_in[12];
    const float* gbhh = (const float*)d_in[13];
    const float* r1W  = (const float*)d_in[14];
    const float* r1b  = (const float*)d_in[15];
    const float* r2W  = (const float*)d_in[16];
    const float* r2b  = (const float*)d_in[17];
    const float* hx0  = (const float*)d_in[18];
    float* out = (float*)d_out;

    // ---- workspace carve-up ----
    char* w = (char*)d_ws;
    float* pooled = (float*)w; w += (size_t)T_STEPS * H2D * 4;      // 32 KB
    float* hx_all = (float*)w; w += (size_t)T_STEPS * GD * 4;       // 64 KB
    float* W1     = (float*)w; w += (size_t)256 * 384 * 4;          // 384 KB
    float* gi_all = (float*)w; w += (size_t)T_STEPS * 768 * 4;      // 192 KB
    float* ppart  = (float*)w; w += (size_t)T_STEPS * 16 * H2D * 4; // 512 KB
    unsigned int* cnt = (unsigned int*)w; w += 256;                 // 64 ctr + pad
    size_t fixed = (size_t)(w - (char*)d_ws);

    int Tc = 64;
    while (Tc > 1) {
        size_t need = fixed + (size_t)Tc * (8192 + 2ull * 2048 * 384 * 4);
        if (need <= ws_size) break;
        Tc >>= 1;
    }
    float* norms = (float*)w; w += (size_t)Tc * NN * 4;
    float* bufA  = (float*)w; w += (size_t)Tc * NN * C1D * 4;
    float* bufB  = (float*)w;

    prep_W1<<<(256 * 384 + 255) / 256, 256, 0, stream>>>(fc1, W1, cnt);

    for (int t0 = 0; t0 < T_STEPS; t0 += Tc) {
        int M = Tc * NN;
        norms_kernel      <<<Tc * NN / 4, 256, 0, stream>>>(h, norms, t0);
        input_attn_kernel <<<Tc * NN / 2, 256, 0, stream>>>(h, ng, norms, bufA, t0);
        matmul_f32<<<dim3(384 / 64, M / 64), 256, 0, stream>>>(bufA, W1, bufB, M, 384, 256);
        gat_heads_kernel  <<<Tc * NN, 192, 0, stream>>>(bufB, ng, bufA);
        matmul_f32<<<dim3(128 / 64, M / 64), 256, 0, stream>>>(bufA, fc2, bufB, M, 128, 384);
        gat_final_kernel  <<<Tc * NN / 4, 256, 0, stream>>>(bufB, ng, bufA);
        pool_part_kernel  <<<Tc * 16, 128, 0, stream>>>(bufA, ppart);
        pool_reduce_kernel<<<Tc, 128, 0, stream>>>(ppart, pooled, t0);
    }

    gi_all_kernel<<<T_STEPS * 3, 256, 0, stream>>>(gWih, gbih, pooled, gi_all);
    gru_reg_kernel<<<GRU_NB, 768, 0, stream>>>(gWhh, gbhh, gi_all, hx0, hx_all, cnt);
    res_sir_kernel<<<T_STEPS, 128, 0, stream>>>(hx_all, It, Rt, r1W, r1b, r2W, r2b,
                                                I_, R_, S_, Npop, out);
}

// Round 7
// 1601.557 us; speedup vs baseline: 1.0731x; 1.0731x over previous
//
#include <hip/hip_runtime.h>
#include <hip/hip_bf16.h>
#include <math.h>

// Problem constants
#define T_STEPS 64
#define NN      2048
#define KN      32
#define IND     256
#define H1D     128
#define C1D     384   // HEADS*H1
#define H2D     128
#define GD      256
#define PD      60
#define GRU_NB  8     // cooperating blocks for the GRU

// bit-reversed 5-bit order (involution): loading rows in this order makes
// lane l end up owning neighbor l's dot after the butterfly reduce.
#define BITREV5_INIT {0,16,8,24,4,20,12,28,2,18,10,26,6,22,14,30, \
                      1,17,9,25,5,21,13,29,3,19,11,27,7,23,15,31}

__device__ __forceinline__ float bcast_lane(float v, int lane_imm) {
    return __uint_as_float(__builtin_amdgcn_readlane(__float_as_uint(v), lane_imm));
}

// Butterfly stages 2..6 on 16 stage-1-combined partials.
// Input: part[i] = stage-1 combine of slots (BR[i], BR[i+16]).
// Output: lane l holds full 64-lane sum of slot (l & 31).
__device__ __forceinline__ float xpose_reduce16(float part[16], int lane) {
#pragma unroll
    for (int i = 0; i < 8; ++i) {
        float send = (lane & 2) ? part[i] : part[i + 8];
        float keep = (lane & 2) ? part[i + 8] : part[i];
        part[i] = keep + __shfl_xor(send, 2);
    }
#pragma unroll
    for (int i = 0; i < 4; ++i) {
        float send = (lane & 4) ? part[i] : part[i + 4];
        float keep = (lane & 4) ? part[i + 4] : part[i];
        part[i] = keep + __shfl_xor(send, 4);
    }
#pragma unroll
    for (int i = 0; i < 2; ++i) {
        float send = (lane & 8) ? part[i] : part[i + 2];
        float keep = (lane & 8) ? part[i + 2] : part[i];
        part[i] = keep + __shfl_xor(send, 8);
    }
    {
        float send = (lane & 16) ? part[0] : part[1];
        float keep = (lane & 16) ? part[1] : part[0];
        part[0] = keep + __shfl_xor(send, 16);
    }
    return part[0] + __shfl_xor(part[0], 32);
}

// ---------------------------------------------------------------------------
// K1: row norms of h[t]  (one wave per node)
// ---------------------------------------------------------------------------
__global__ __launch_bounds__(256) void norms_kernel(const float* __restrict__ h,
                                                    float* __restrict__ norms,
                                                    int t_base) {
    int gw   = (int)((blockIdx.x * blockDim.x + threadIdx.x) >> 6);
    int lane = threadIdx.x & 63;
    int n    = gw & (NN - 1);
    int tloc = gw >> 11;
    const float* row = h + ((size_t)(t_base + tloc) * NN + n) * IND;
    float s = 0.f;
#pragma unroll
    for (int q = 0; q < 4; ++q) { float v = row[lane + 64 * q]; s += v * v; }
#pragma unroll
    for (int off = 32; off > 0; off >>= 1) s += __shfl_xor(s, off);
    if (lane == 0) norms[(size_t)tloc * NN + n] = sqrtf(s);
}

// ---------------------------------------------------------------------------
// K2: input attention. 2 waves per (t,n) (128 dims each); rows kept in VGPRs
// (keep-alive asm prevents rematerialization), scalar (SGPR) row bases.
// ---------------------------------------------------------------------------
__global__ __launch_bounds__(256, 4) void input_attn_kernel(const float* __restrict__ h,
                                                            const int* __restrict__ neigh,
                                                            const float* __restrict__ norms,
                                                            float* __restrict__ ih,
                                                            int t_base) {
    const int BR[32] = BITREV5_INIT;
    __shared__ float hd_s[2][2][32];
    int wave    = threadIdx.x >> 6;   // 0..3
    int nodeloc = wave >> 1;          // 0..1
    int half    = wave & 1;           // which 128-dim half
    int lane    = threadIdx.x & 63;
    int gw   = (int)((blockIdx.x << 1) | nodeloc);
    int n    = gw & (NN - 1);
    int tloc = gw >> 11;
    const float* hT  = h + (size_t)(t_base + tloc) * NN * IND;
    const float* nrm = norms + (size_t)tloc * NN;

    const float* dst = hT + (size_t)n * IND + half * 128;
    float d0 = dst[lane], d1 = dst[lane + 64];

    int   jreg = neigh[n * KN + (lane & 31)];
    float nj   = nrm[jreg];
    float ndst = nrm[n];

    float r0[32], r1[32], comb[16];
#pragma unroll
    for (int i = 0; i < 16; ++i) {
        int sja = __builtin_amdgcn_readlane(jreg, BR[i]);
        int sjb = __builtin_amdgcn_readlane(jreg, BR[i + 16]);
        const float* sa = hT + (size_t)sja * IND + half * 128;
        const float* sb = hT + (size_t)sjb * IND + half * 128;
        r0[i]      = sa[lane]; r1[i]      = sa[lane + 64];
        r0[i + 16] = sb[lane]; r1[i + 16] = sb[lane + 64];
        float pa = r0[i] * d0 + r1[i] * d1;
        float pb = r0[i + 16] * d0 + r1[i + 16] * d1;
        float send = (lane & 1) ? pa : pb;
        float keep = (lane & 1) ? pb : pa;
        comb[i] = keep + __shfl_xor(send, 1);
    }
#pragma unroll
    for (int i = 0; i < 32; ++i) asm volatile("" : "+v"(r0[i]), "+v"(r1[i]));
    float hdot = xpose_reduce16(comb, lane);   // half-dot of neighbor (lane&31)
    if (lane < 32) hd_s[nodeloc][half][lane] = hdot;
    __syncthreads();
    float dot = hdot + hd_s[nodeloc][half ^ 1][lane & 31];

    float r  = dot / (nj * ndst);
    float r2 = r * r;
    float e  = r2 * r2;

    float a0 = 0.f, a1 = 0.f;
#pragma unroll
    for (int i = 0; i < 32; ++i) {
        float ek = bcast_lane(e, BR[i]);
        a0 += ek * r0[i];
        a1 += ek * r1[i];
    }
    float* orow = ih + (size_t)gw * IND + half * 128;
    orow[lane]      = a0;
    orow[lane + 64] = a1;
}

// ---------------------------------------------------------------------------
// K3/K6: generic fp32 tiled GEMM  C[M,N] = A[M,K] @ B[K,N]
// ---------------------------------------------------------------------------
__global__ __launch_bounds__(256) void matmul_f32(const float* __restrict__ A,
                                                  const float* __restrict__ B,
                                                  float* __restrict__ C,
                                                  int M, int N, int K) {
    __shared__ float As[16][65];
    __shared__ float Bs[16][68];
    int tid  = threadIdx.x;
    int row0 = blockIdx.y * 64;
    int col0 = blockIdx.x * 64;
    int tr = tid >> 4, tc = tid & 15;
    float acc[4][4] = {};
    int la_m = tid >> 2;
    int la_k = (tid & 3) * 4;
    int lb_k = tid >> 4;
    int lb_n = (tid & 15) * 4;
    for (int k0 = 0; k0 < K; k0 += 16) {
        float4 av = *(const float4*)(A + (size_t)(row0 + la_m) * K + k0 + la_k);
        float4 bv = *(const float4*)(B + (size_t)(k0 + lb_k) * N + col0 + lb_n);
        __syncthreads();
        As[la_k + 0][la_m] = av.x; As[la_k + 1][la_m] = av.y;
        As[la_k + 2][la_m] = av.z; As[la_k + 3][la_m] = av.w;
        *(float4*)&Bs[lb_k][lb_n] = bv;
        __syncthreads();
#pragma unroll
        for (int kk = 0; kk < 16; ++kk) {
            float a[4], b[4];
#pragma unroll
            for (int r = 0; r < 4; ++r) a[r] = As[kk][tr * 4 + r];
#pragma unroll
            for (int c = 0; c < 4; ++c) b[c] = Bs[kk][tc * 4 + c];
#pragma unroll
            for (int r = 0; r < 4; ++r)
#pragma unroll
                for (int c = 0; c < 4; ++c) acc[r][c] += a[r] * b[c];
        }
    }
#pragma unroll
    for (int r = 0; r < 4; ++r) {
        float4 v = { acc[r][0], acc[r][1], acc[r][2], acc[r][3] };
        *(float4*)(C + (size_t)(row0 + tr * 4 + r) * N + col0 + tc * 4) = v;
    }
}

// ---------------------------------------------------------------------------
// K4: 3-head GAT + relu. One block (192 thr, wave=head) per (t,n), lane=d.
// Rows kept in VGPRs (keep-alive); scalar row bases via readlane.
// ---------------------------------------------------------------------------
__global__ __launch_bounds__(192, 4) void gat_heads_kernel(const float* __restrict__ z1,
                                                           const int* __restrict__ neigh,
                                                           float* __restrict__ c) {
    const int BR[32] = BITREV5_INIT;
    int n    = blockIdx.x & (NN - 1);
    const float* ztbl = z1 + (size_t)(blockIdx.x >> 11) * NN * C1D;
    int head = threadIdx.x >> 6;
    int lane = threadIdx.x & 63;

    const float* dst = ztbl + (size_t)n * C1D + head * H1D;
    float d0 = dst[lane], d1 = dst[lane + 64];
    int jreg = neigh[n * KN + (lane & 31)];

    float r0[32], r1[32], comb[16];
#pragma unroll
    for (int i = 0; i < 16; ++i) {
        int sja = __builtin_amdgcn_readlane(jreg, BR[i]);
        int sjb = __builtin_amdgcn_readlane(jreg, BR[i + 16]);
        const float* sa = ztbl + (size_t)sja * C1D + head * H1D;
        const float* sb = ztbl + (size_t)sjb * C1D + head * H1D;
        r0[i]      = sa[lane]; r1[i]      = sa[lane + 64];
        r0[i + 16] = sb[lane]; r1[i + 16] = sb[lane + 64];
        float pa = r0[i] * d0 + r1[i] * d1;
        float pb = r0[i + 16] * d0 + r1[i + 16] * d1;
        float send = (lane & 1) ? pa : pb;
        float keep = (lane & 1) ? pb : pa;
        comb[i] = keep + __shfl_xor(send, 1);
    }
#pragma unroll
    for (int i = 0; i < 32; ++i) asm volatile("" : "+v"(r0[i]), "+v"(r1[i]));
    float dot = xpose_reduce16(comb, lane);   // lane l: dot of neighbor (l&31)

    float m = dot;
#pragma unroll
    for (int off = 16; off > 0; off >>= 1) m = fmaxf(m, __shfl_xor(m, off));
    float p = __expf(dot - m);
    float s = p;
#pragma unroll
    for (int off = 16; off > 0; off >>= 1) s += __shfl_xor(s, off);
    p /= s;

    float a0 = 0.f, a1 = 0.f;
#pragma unroll
    for (int i = 0; i < 32; ++i) {
        float pk = bcast_lane(p, BR[i]);
        a0 += pk * r0[i];
        a1 += pk * r1[i];
    }
    size_t base = (size_t)blockIdx.x * C1D + (size_t)head * H1D;
    c[base + lane]      = fmaxf(a0, 0.f);
    c[base + lane + 64] = fmaxf(a1, 0.f);
}

// ---------------------------------------------------------------------------
// K7: final GAT on z2 (d=128) + relu -> c2. One wave per (t,n), rows in VGPRs.
// ---------------------------------------------------------------------------
__global__ __launch_bounds__(256, 4) void gat_final_kernel(const float* __restrict__ z2,
                                                           const int* __restrict__ neigh,
                                                           float* __restrict__ c2) {
    const int BR[32] = BITREV5_INIT;
    int gw   = (int)((blockIdx.x << 2) | (threadIdx.x >> 6));
    int n    = gw & (NN - 1);
    const float* ztbl = z2 + (size_t)(gw >> 11) * NN * H2D;
    int lane = threadIdx.x & 63;

    const float* dst = ztbl + (size_t)n * H2D;
    float d0 = dst[lane], d1 = dst[lane + 64];
    int jreg = neigh[n * KN + (lane & 31)];

    float r0[32], r1[32], comb[16];
#pragma unroll
    for (int i = 0; i < 16; ++i) {
        int sja = __builtin_amdgcn_readlane(jreg, BR[i]);
        int sjb = __builtin_amdgcn_readlane(jreg, BR[i + 16]);
        const float* sa = ztbl + (size_t)sja * H2D;
        const float* sb = ztbl + (size_t)sjb * H2D;
        r0[i]      = sa[lane]; r1[i]      = sa[lane + 64];
        r0[i + 16] = sb[lane]; r1[i + 16] = sb[lane + 64];
        float pa = r0[i] * d0 + r1[i] * d1;
        float pb = r0[i + 16] * d0 + r1[i + 16] * d1;
        float send = (lane & 1) ? pa : pb;
        float keep = (lane & 1) ? pb : pa;
        comb[i] = keep + __shfl_xor(send, 1);
    }
#pragma unroll
    for (int i = 0; i < 32; ++i) asm volatile("" : "+v"(r0[i]), "+v"(r1[i]));
    float dot = xpose_reduce16(comb, lane);

    float m = dot;
#pragma unroll
    for (int off = 16; off > 0; off >>= 1) m = fmaxf(m, __shfl_xor(m, off));
    float p = __expf(dot - m);
    float s = p;
#pragma unroll
    for (int off = 16; off > 0; off >>= 1) s += __shfl_xor(s, off);
    p /= s;

    float a0 = 0.f, a1 = 0.f;
#pragma unroll
    for (int i = 0; i < 32; ++i) {
        float pk = bcast_lane(p, BR[i]);
        a0 += pk * r0[i];
        a1 += pk * r1[i];
    }
    c2[(size_t)gw * H2D + lane]      = fmaxf(a0, 0.f);
    c2[(size_t)gw * H2D + lane + 64] = fmaxf(a1, 0.f);
}

// ---------------------------------------------------------------------------
// K8: pooled[t][j] = max_n c2[t][n][j]  — two stage for grid parallelism
// ---------------------------------------------------------------------------
__global__ __launch_bounds__(128) void pool_part_kernel(const float* __restrict__ c2,
                                                        float* __restrict__ ppart) {
    int j = threadIdx.x;
    int tloc  = blockIdx.x >> 4;
    int slice = blockIdx.x & 15;
    const float* base = c2 + ((size_t)tloc * NN + slice * 128) * H2D;
    float mx = 0.f;
    for (int q = 0; q < 128; ++q) mx = fmaxf(mx, base[(size_t)q * H2D + j]);
    ppart[(size_t)blockIdx.x * H2D + j] = mx;
}
__global__ __launch_bounds__(128) void pool_reduce_kernel(const float* __restrict__ ppart,
                                                          float* __restrict__ pooled,
                                                          int t_base) {
    int j = threadIdx.x;
    const float* base = ppart + (size_t)blockIdx.x * 16 * H2D;
    float mx = 0.f;
#pragma unroll
    for (int q = 0; q < 16; ++q) mx = fmaxf(mx, base[(size_t)q * H2D + j]);
    pooled[(t_base + blockIdx.x) * H2D + j] = mx;
}

// ---------------------------------------------------------------------------
// prep: fc1 (3,256,128) -> W1 (256,384); zero GRU arrival counters
// ---------------------------------------------------------------------------
__global__ void prep_W1(const float* __restrict__ fc1, float* __restrict__ W1,
                        unsigned int* __restrict__ cnt) {
    int i = blockIdx.x * 256 + threadIdx.x;
    if (i < 256 * 384) {
        int d = i / 384, cf = i % 384;
        int hd = cf >> 7, j = cf & 127;
        W1[i] = fc1[(size_t)hd * 256 * 128 + (size_t)d * 128 + j];
    }
    if (i < T_STEPS) cnt[i] = 0u;
}

// ---------------------------------------------------------------------------
// gi_all[t][o] = Wih[o,:] . pooled[t,:] + bih[o]   (parallel over t)
// ---------------------------------------------------------------------------
__global__ __launch_bounds__(256) void gi_all_kernel(const float* __restrict__ Wih,
                                                     const float* __restrict__ bih,
                                                     const float* __restrict__ pooled,
                                                     float* __restrict__ gi_all) {
    __shared__ float p_s[H2D];
    int t  = blockIdx.x / 3;
    int ob = (blockIdx.x % 3) * 256;
    if (threadIdx.x < H2D) p_s[threadIdx.x] = pooled[t * H2D + threadIdx.x];
    __syncthreads();
    int o = ob + threadIdx.x;
    float acc = bih[o];
    const float* wr = Wih + (size_t)o * H2D;
#pragma unroll 4
    for (int d = 0; d < H2D; ++d) acc += wr[d] * p_s[d];
    gi_all[t * 768 + o] = acc;
}

// ---------------------------------------------------------------------------
// GRU: 8 cooperating blocks, Whh register-resident (no per-step weight re-read).
// ---------------------------------------------------------------------------
__global__ __launch_bounds__(768) void gru_reg_kernel(const float* __restrict__ Whh,
                                                      const float* __restrict__ bhh,
                                                      const float* __restrict__ gi_all,
                                                      const float* __restrict__ hx0,
                                                      float* hx_all,
                                                      unsigned int* cnt) {
    __shared__ float4 hx_pad[72];                 // padded: idx (g,i) -> g*9+i
    __shared__ __align__(16) float hx_lin[GD];    // linear copy for hx_old
    __shared__ float gh_s[96];
    int b   = blockIdx.x;
    int tid = threadIdx.x;
    int row_local = tid >> 3;      // 0..95
    int sub       = tid & 7;       // 0..7
    int chunk     = row_local >> 5;
    int r_in      = row_local & 31;
    int grow      = chunk * GD + b * 32 + r_in;

    float4 wreg[8];
    const float4* wrow = (const float4*)(Whh + (size_t)grow * GD + sub * 32);
#pragma unroll
    for (int i = 0; i < 8; ++i) wreg[i] = wrow[i];
    float bias = (sub == 0) ? bhh[grow] : 0.f;

    for (int t = 0; t < T_STEPS; ++t) {
        if (t > 0) {
            if (tid == 0) {
                while (__hip_atomic_load(&cnt[t - 1], __ATOMIC_ACQUIRE,
                                         __HIP_MEMORY_SCOPE_AGENT) < GRU_NB)
                    __builtin_amdgcn_s_sleep(1);
            }
            __syncthreads();
        }
        const float* hsrc = (t == 0) ? hx0 : (hx_all + (size_t)(t - 1) * GD);
        if (tid < 64) {
            float4 v;
            v.x = __hip_atomic_load(hsrc + tid * 4 + 0, __ATOMIC_RELAXED, __HIP_MEMORY_SCOPE_AGENT);
            v.y = __hip_atomic_load(hsrc + tid * 4 + 1, __ATOMIC_RELAXED, __HIP_MEMORY_SCOPE_AGENT);
            v.z = __hip_atomic_load(hsrc + tid * 4 + 2, __ATOMIC_RELAXED, __HIP_MEMORY_SCOPE_AGENT);
            v.w = __hip_atomic_load(hsrc + tid * 4 + 3, __ATOMIC_RELAXED, __HIP_MEMORY_SCOPE_AGENT);
            hx_pad[(tid >> 3) * 9 + (tid & 7)] = v;
            ((float4*)hx_lin)[tid] = v;
        }
        __syncthreads();

        float acc = 0.f;
#pragma unroll
        for (int i = 0; i < 8; ++i) {
            float4 hv = hx_pad[sub * 9 + i];
            float4 wv = wreg[i];
            acc += wv.x * hv.x + wv.y * hv.y + wv.z * hv.z + wv.w * hv.w;
        }
        acc += __shfl_xor(acc, 1);
        acc += __shfl_xor(acc, 2);
        acc += __shfl_xor(acc, 4);
        if (sub == 0) gh_s[row_local] = acc + bias;
        __syncthreads();

        if (tid < 32) {
            int u = b * 32 + tid;
            float gi_r = gi_all[t * 768 + u];
            float gi_z = gi_all[t * 768 + 256 + u];
            float gi_n = gi_all[t * 768 + 512 + u];
            float r  = 1.f / (1.f + expf(-(gi_r + gh_s[tid])));
            float zg = 1.f / (1.f + expf(-(gi_z + gh_s[32 + tid])));
            float nn = tanhf(gi_n + r * gh_s[64 + tid]);
            float hnew = (1.f - zg) * nn + zg * hx_lin[u];
            __hip_atomic_store(&hx_all[(size_t)t * GD + u], hnew,
                               __ATOMIC_RELAXED, __HIP_MEMORY_SCOPE_AGENT);
            __threadfence();
        }
        __syncthreads();
        if (tid == 0)
            __hip_atomic_fetch_add(&cnt[t], 1u, __ATOMIC_RELEASE,
                                   __HIP_MEMORY_SCOPE_AGENT);
    }
}

// ---------------------------------------------------------------------------
// res heads + SIR scan. One block per t.
// ---------------------------------------------------------------------------
__global__ __launch_bounds__(128) void res_sir_kernel(const float* __restrict__ hx_all,
                                                      const float* __restrict__ It,
                                                      const float* __restrict__ Rt,
                                                      const float* __restrict__ r1W,
                                                      const float* __restrict__ r1b,
                                                      const float* __restrict__ r2W,
                                                      const float* __restrict__ r2b,
                                                      const float* __restrict__ I,
                                                      const float* __restrict__ R,
                                                      const float* __restrict__ S,
                                                      const float* __restrict__ Npop,
                                                      float* __restrict__ out) {
    __shared__ float nhx[258];
    __shared__ float ab_s[2];
    int t = blockIdx.x, tid = threadIdx.x;
    for (int i = tid; i < GD; i += 128) nhx[i] = hx_all[t * GD + i];
    if (tid == 0) { nhx[256] = It[t]; nhx[257] = Rt[t]; }
    __syncthreads();
    if (tid < 120) {
        float acc = r1b[tid];
        const float* wr = r1W + tid * 258;
        for (int d = 0; d < 258; ++d) acc += wr[d] * nhx[d];
        int idx = t * 60 + (tid >> 1);
        if (tid & 1) out[3840 + idx] = acc;
        else         out[idx] = acc;
    }
    if (tid == 120 || tid == 121) {
        int q = tid - 120;
        float acc = r2b[q];
        const float* wr = r2W + q * 258;
        for (int d = 0; d < 258; ++d) acc += wr[d] * nhx[d];
        ab_s[q] = acc;
    }
    __syncthreads();
    if (tid == 0) {
        float a_s = 1.f / (1.f + expf(-ab_s[0]));
        float b_s = 1.f / (1.f + expf(-ab_s[1]));
        float Np = Npop[0];
        float lI = I[t], lR = R[t], lS = S[t];
        for (int p = 0; p < PD; ++p) {
            float dI = a_s * lI * (lS / Np) - b_s * lI;
            float dR = b_s * lI;
            lI += dI;
            lR += dR;
            lS = Np - lI - lR;
            out[7680  + t * 60 + p] = dI;
            out[11520 + t * 60 + p] = dR;
        }
    }
}

// ---------------------------------------------------------------------------
extern "C" void kernel_launch(void* const* d_in, const int* in_sizes, int n_in,
                              void* d_out, int out_size, void* d_ws, size_t ws_size,
                              hipStream_t stream) {
    const float* h    = (const float*)d_in[0];
    const int*   ng   = (const int*)  d_in[1];
    const float* Npop = (const float*)d_in[2];
    const float* I_   = (const float*)d_in[3];
    const float* R_   = (const float*)d_in[4];
    const float* S_   = (const float*)d_in[5];
    const float* It   = (const float*)d_in[6];
    const float* Rt   = (const float*)d_in[7];
    const float* fc1  = (const float*)d_in[8];
    const float* fc2  = (const float*)d_in[9];
    const float* gWih = (const float*)d_in[10];
    const float* gWhh = (const float*)d_in[11];
    const float* gbih = (const float*)d_in[12];
    const float* gbhh = (const float*)d_in[13];
    const float* r1W  = (const float*)d_in[14];
    const float* r1b  = (const float*)d_in[15];
    const float* r2W  = (const float*)d_in[16];
    const float* r2b  = (const float*)d_in[17];
    const float* hx0  = (const float*)d_in[18];
    float* out = (float*)d_out;

    // ---- workspace carve-up ----
    char* w = (char*)d_ws;
    float* pooled = (float*)w; w += (size_t)T_STEPS * H2D * 4;      // 32 KB
    float* hx_all = (float*)w; w += (size_t)T_STEPS * GD * 4;       // 64 KB
    float* W1     = (float*)w; w += (size_t)256 * 384 * 4;          // 384 KB
    float* gi_all = (float*)w; w += (size_t)T_STEPS * 768 * 4;      // 192 KB
    float* ppart  = (float*)w; w += (size_t)T_STEPS * 16 * H2D * 4; // 512 KB
    unsigned int* cnt = (unsigned int*)w; w += 256;                 // 64 ctr + pad
    size_t fixed = (size_t)(w - (char*)d_ws);

    // Tc=16: per-chunk working set (h slice + bufA + bufB ~ 150 MB) fits the
    // 256 MB L3, so gathers and GEMM operands stay Infinity-Cache-resident.
    int Tc = 16;
    while (Tc > 1) {
        size_t need = fixed + (size_t)Tc * (8192 + 2ull * 2048 * 384 * 4);
        if (need <= ws_size) break;
        Tc >>= 1;
    }
    float* norms = (float*)w; w += (size_t)Tc * NN * 4;
    float* bufA  = (float*)w; w += (size_t)Tc * NN * C1D * 4;
    float* bufB  = (float*)w;

    prep_W1<<<(256 * 384 + 255) / 256, 256, 0, stream>>>(fc1, W1, cnt);

    for (int t0 = 0; t0 < T_STEPS; t0 += Tc) {
        int M = Tc * NN;
        norms_kernel      <<<Tc * NN / 4, 256, 0, stream>>>(h, norms, t0);
        input_attn_kernel <<<Tc * NN / 2, 256, 0, stream>>>(h, ng, norms, bufA, t0);
        matmul_f32<<<dim3(384 / 64, M / 64), 256, 0, stream>>>(bufA, W1, bufB, M, 384, 256);
        gat_heads_kernel  <<<Tc * NN, 192, 0, stream>>>(bufB, ng, bufA);
        matmul_f32<<<dim3(128 / 64, M / 64), 256, 0, stream>>>(bufA, fc2, bufB, M, 128, 384);
        gat_final_kernel  <<<Tc * NN / 4, 256, 0, stream>>>(bufB, ng, bufA);
        pool_part_kernel  <<<Tc * 16, 128, 0, stream>>>(bufA, ppart);
        pool_reduce_kernel<<<Tc, 128, 0, stream>>>(ppart, pooled, t0);
    }

    gi_all_kernel<<<T_STEPS * 3, 256, 0, stream>>>(gWih, gbih, pooled, gi_all);
    gru_reg_kernel<<<GRU_NB, 768, 0, stream>>>(gWhh, gbhh, gi_all, hx0, hx_all, cnt);
    res_sir_kernel<<<T_STEPS, 128, 0, stream>>>(hx_all, It, Rt, r1W, r1b, r2W, r2b,
                                                I_, R_, S_, Npop, out);
}